// Round 4
// baseline (2246.266 us; speedup 1.0000x reference)
//
#include <hip/hip_runtime.h>
#include <hip/hip_bf16.h>
#include <stdint.h>

typedef __attribute__((ext_vector_type(8))) short short8;
typedef __attribute__((ext_vector_type(4))) float f32x4;

__device__ __forceinline__ short f2bf_s(float x){
    union { __hip_bfloat16 b; short s; } u; u.b = __float2bfloat16(x); return u.s;
}
__device__ __forceinline__ float bf2f_s(short s){
    union { __hip_bfloat16 b; short s2; } u; u.s2 = s; return __bfloat162float(u.b);
}
__device__ __forceinline__ void load_lds16(const void* g, void* l){
    __builtin_amdgcn_global_load_lds(
        (const __attribute__((address_space(1))) void*)g,
        (__attribute__((address_space(3))) void*)l, 16, 0, 0);
}
__device__ __forceinline__ float sigmoidf_(float x){
    return 1.0f / (1.0f + __expf(-x));
}
// LLC-coherent 16B load (agent-scope atomics bypass XCD L2)
__device__ __forceinline__ uint4 aload16(const unsigned* p){
    unsigned long long a = __hip_atomic_load((const unsigned long long*)p,
                           __ATOMIC_RELAXED, __HIP_MEMORY_SCOPE_AGENT);
    unsigned long long b = __hip_atomic_load((const unsigned long long*)p + 1,
                           __ATOMIC_RELAXED, __HIP_MEMORY_SCOPE_AGENT);
    uint4 r; r.x = (unsigned)a; r.y = (unsigned)(a >> 32);
    r.z = (unsigned)b; r.w = (unsigned)(b >> 32);
    return r;
}

// ---------- conversion kernels ----------

__global__ void k_cvt_x(const float* __restrict__ x, short* __restrict__ xin){
    int q = blockIdx.x * blockDim.x + threadIdx.x;
    if (q >= 8388608) return;
    const float4 v = ((const float4*)x)[q];
    int r = q >> 8;
    int c4 = (q & 255) << 2;
    short4 o;
    o.x = f2bf_s(v.x); o.y = f2bf_s(v.y); o.z = f2bf_s(v.z); o.w = f2bf_s(v.w);
    *(short4*)(xin + (int64_t)r * 2048 + c4) = o;
}

__global__ void k_cvt_stages(const float* __restrict__ st, short* __restrict__ sp){
    int i = blockIdx.x * blockDim.x + threadIdx.x;
    if (i >= 32768 * 96) return;
    int r = i / 96, k = i - r * 96;
    sp[i] = (k < 67) ? f2bf_s(st[(int64_t)r * 67 + k]) : (short)0;
}

__global__ void k_transpose(const float* __restrict__ w, short* __restrict__ wt,
                            int K, int N, int Kpad){
    int i = blockIdx.x * blockDim.x + threadIdx.x;
    if (i >= N * Kpad) return;
    int n = i / Kpad, k = i - n * Kpad;
    wt[i] = (k < K) ? f2bf_s(w[(int64_t)k * N + n]) : (short)0;
}

// zero h_seq/c_seq (2 x 257 x 32768 u32, contiguous); s=0 slices get the
// "valid zero" pattern 0x00010000 (bit16 = sentinel, payload = 0).
__global__ void k_init_seq(uint4* __restrict__ p){
    int i = blockIdx.x * 256 + threadIdx.x;
    if (i >= 4210688) return;
    bool s0 = (i < 8192) | (i >= 2105344 && i < 2105344 + 8192);
    unsigned v = s0 ? 0x10000u : 0u;
    uint4 o; o.x = v; o.y = v; o.z = v; o.w = v;
    p[i] = o;
}

// ---------- bf16 MFMA GEMM (m97 structure, unchanged) ----------
__global__ __launch_bounds__(256) void k_gemm(
    const short* __restrict__ A, int lda,
    const short* __restrict__ BT, int ldb,
    const float* __restrict__ bias,
    int K, int flags,
    float* __restrict__ Cf, short* __restrict__ Cb, int ldc)
{
    __shared__ __align__(16) short At[128 * 32];
    __shared__ __align__(16) short Bt[128 * 32];
    const int tid = threadIdx.x;
    const int lane = tid & 63, w = tid >> 6;
    const int q = lane >> 4, m = lane & 15;
    const int wr = w >> 1, wc = w & 1;
    const int bm = blockIdx.y, bn = blockIdx.x;

    const short* Ablk = A + (int64_t)bm * 128 * lda;
    const short* Bblk = BT + (int64_t)bn * 128 * ldb;

    f32x4 acc[4][4] = {};

    for (int k0 = 0; k0 < K; k0 += 32){
#pragma unroll
        for (int call = 0; call < 2; ++call){
            int chunk = (call * 4 + w) * 64 + lane;
            int row = chunk >> 2, co = (chunk & 3) * 8;
            load_lds16(Ablk + (int64_t)row * lda + k0 + co, At + (call * 4 + w) * 512);
            load_lds16(Bblk + (int64_t)row * ldb + k0 + co, Bt + (call * 4 + w) * 512);
        }
        __syncthreads();
        short8 af[4], bfr[4];
#pragma unroll
        for (int mt = 0; mt < 4; ++mt)
            af[mt] = *(const short8*)(At + (wr * 64 + mt * 16 + m) * 32 + q * 8);
#pragma unroll
        for (int nt = 0; nt < 4; ++nt)
            bfr[nt] = *(const short8*)(Bt + (wc * 64 + nt * 16 + m) * 32 + q * 8);
#pragma unroll
        for (int mt = 0; mt < 4; ++mt)
#pragma unroll
            for (int nt = 0; nt < 4; ++nt)
                acc[mt][nt] = __builtin_amdgcn_mfma_f32_16x16x32_bf16(
                    af[mt], bfr[nt], acc[mt][nt], 0, 0, 0);
        __syncthreads();
    }

#pragma unroll
    for (int mt = 0; mt < 4; ++mt){
#pragma unroll
        for (int nt = 0; nt < 4; ++nt){
            int col = bn * 128 + wc * 64 + nt * 16 + m;
            float bv = bias[col];
#pragma unroll
            for (int rg = 0; rg < 4; ++rg){
                int row = bm * 128 + wr * 64 + mt * 16 + q * 4 + rg;
                float v = acc[mt][nt][rg] + bv;
                if (flags & 1) v = fmaxf(v, 0.0f);
                if (flags & 2){
                    Cb[(int64_t)row * ldc + col] = f2bf_s(v);
                } else if (flags & 4){
                    int s = row & 255, b = row >> 8;
                    Cf[((int64_t)s * 128 + b) * 1024 + col] = v;
                } else {
                    Cf[(int64_t)row * ldc + col] = v;
                }
            }
        }
    }
}

// ---------- TLSTM scan v2: 128 single-wave blocks, weights in VGPRs ----------
// Wave (rg, cg) owns batch rows [16rg,16rg+16) x h-cols [16cg,16cg+16).
// 5 weight tiles (f,i,o,g: W_all cols; d: W_d cols) as hi/lo bf16 B-fragments
// in registers (320 VGPR; launch_bounds(64,1) -> 512 budget). No LDS, no
// barriers, no counter: producers set bit16 (sentinel) in every packed h/c
// word (lo-mantissa LSB, <=2^-17 relative); h/c_seq pre-zeroed so
// valid <=> written. Fast path: plain cached loads; on any invalid word the
// wave reloads via agent-scope atomics (LLC-coherent) and recomputes.
__global__ __launch_bounds__(64, 1) void k_scan2(
    const float* __restrict__ W_all, const float* __restrict__ W_all_b,
    const float* __restrict__ W_d,   const float* __restrict__ W_d_b,
    const float* __restrict__ u,     const float* __restrict__ tsp,
    unsigned* __restrict__ h_seq,    // [257][128][256] packed bf16 hi|lo
    unsigned* __restrict__ c_seq,
    float* __restrict__ feat)        // [B][S][H]
{
    const int lane = threadIdx.x;
    const int q = lane >> 4, n = lane & 15;
    const int rg = blockIdx.x & 7, cg = blockIdx.x >> 3;  // rg=XCD-local (perf only)
    const int row0 = rg * 16, col0 = cg * 16;
    const int gcol = col0 + n;

    // ---- one-time: weight B-fragments into registers (hi/lo bf16) ----
    // B-frag layout (validated R1-R3): lane holds W[k = kb*32 + q*8 + j][col0 + n]
    short8 wH[5][8], wL[5][8];
#pragma unroll
    for (int t = 0; t < 5; ++t){
        const float* Wsrc = (t < 4) ? (W_all + t * 256 + gcol) : (W_d + gcol);
        const int ld = (t < 4) ? 1024 : 256;
#pragma unroll
        for (int kb = 0; kb < 8; ++kb){
            short8 hv, lv;
#pragma unroll
            for (int j = 0; j < 8; ++j){
                float v = Wsrc[(int64_t)(kb * 32 + q * 8 + j) * ld];
                short hi = f2bf_s(v);
                hv[j] = hi; lv[j] = f2bf_s(v - bf2f_s(hi));
            }
            wH[t][kb] = hv; wL[t][kb] = lv;
        }
    }

    const float bF = W_all_b[gcol], bI = W_all_b[256 + gcol],
                bO = W_all_b[512 + gcol], bG = W_all_b[768 + gcol],
                bD = W_d_b[gcol];

    float c_reg[4] = {0.f, 0.f, 0.f, 0.f};

    for (int s = 0; s < 256; ++s){
        // prefetch u/tsp for the 4 owned rows (issued before the h-wait)
        float uF[4], uI[4], uO[4], uG[4], tt[4];
#pragma unroll
        for (int r2 = 0; r2 < 4; ++r2){
            int gb = row0 + q * 4 + r2;
            const float* ur = u + ((int64_t)s * 128 + gb) * 1024;
            uF[r2] = ur[gcol];        uI[r2] = ur[256 + gcol];
            uO[r2] = ur[512 + gcol];  uG[r2] = ur[768 + gcol];
            tt[r2] = tsp[gb * 256 + s];
        }

        const unsigned* hs = h_seq + (int64_t)s * 32768 + (row0 + n) * 256 + q * 8;
        const unsigned* cs = c_seq + (int64_t)s * 32768 + (row0 + n) * 256 + q * 8;

        f32x4 acc0, acc1, acc2, acc3, acc4;
        for (int it = 0; ; ++it){
            acc0 = f32x4{0,0,0,0}; acc1 = acc0; acc2 = acc0; acc3 = acc0; acc4 = acc0;
            unsigned okb = 0xFFFFFFFFu;
#pragma unroll
            for (int kb = 0; kb < 8; ++kb){
                const unsigned* ph = hs + kb * 32;
                const unsigned* pc = cs + kb * 32;
                uint4 h0, h1, c0, c1;
                if (it == 0){
                    h0 = *(const uint4*)ph; h1 = *(const uint4*)(ph + 4);
                    c0 = *(const uint4*)pc; c1 = *(const uint4*)(pc + 4);
                } else {
                    h0 = aload16(ph); h1 = aload16(ph + 4);
                    c0 = aload16(pc); c1 = aload16(pc + 4);
                }
                okb &= h0.x & h0.y & h0.z & h0.w & h1.x & h1.y & h1.z & h1.w
                     & c0.x & c0.y & c0.z & c0.w & c1.x & c1.y & c1.z & c1.w;
                union { short8 v; unsigned u32[4]; } ah, al, ch, cl;
                ah.u32[0] = __builtin_amdgcn_perm(h0.y, h0.x, 0x05040100u);
                ah.u32[1] = __builtin_amdgcn_perm(h0.w, h0.z, 0x05040100u);
                ah.u32[2] = __builtin_amdgcn_perm(h1.y, h1.x, 0x05040100u);
                ah.u32[3] = __builtin_amdgcn_perm(h1.w, h1.z, 0x05040100u);
                al.u32[0] = __builtin_amdgcn_perm(h0.y, h0.x, 0x07060302u);
                al.u32[1] = __builtin_amdgcn_perm(h0.w, h0.z, 0x07060302u);
                al.u32[2] = __builtin_amdgcn_perm(h1.y, h1.x, 0x07060302u);
                al.u32[3] = __builtin_amdgcn_perm(h1.w, h1.z, 0x07060302u);
                ch.u32[0] = __builtin_amdgcn_perm(c0.y, c0.x, 0x05040100u);
                ch.u32[1] = __builtin_amdgcn_perm(c0.w, c0.z, 0x05040100u);
                ch.u32[2] = __builtin_amdgcn_perm(c1.y, c1.x, 0x05040100u);
                ch.u32[3] = __builtin_amdgcn_perm(c1.w, c1.z, 0x05040100u);
                cl.u32[0] = __builtin_amdgcn_perm(c0.y, c0.x, 0x07060302u);
                cl.u32[1] = __builtin_amdgcn_perm(c0.w, c0.z, 0x07060302u);
                cl.u32[2] = __builtin_amdgcn_perm(c1.y, c1.x, 0x07060302u);
                cl.u32[3] = __builtin_amdgcn_perm(c1.w, c1.z, 0x07060302u);
                // bf16x3: hi*hi + hi*lo + lo*hi
                acc0 = __builtin_amdgcn_mfma_f32_16x16x32_bf16(ah.v, wH[0][kb], acc0, 0,0,0);
                acc0 = __builtin_amdgcn_mfma_f32_16x16x32_bf16(ah.v, wL[0][kb], acc0, 0,0,0);
                acc0 = __builtin_amdgcn_mfma_f32_16x16x32_bf16(al.v, wH[0][kb], acc0, 0,0,0);
                acc1 = __builtin_amdgcn_mfma_f32_16x16x32_bf16(ah.v, wH[1][kb], acc1, 0,0,0);
                acc1 = __builtin_amdgcn_mfma_f32_16x16x32_bf16(ah.v, wL[1][kb], acc1, 0,0,0);
                acc1 = __builtin_amdgcn_mfma_f32_16x16x32_bf16(al.v, wH[1][kb], acc1, 0,0,0);
                acc2 = __builtin_amdgcn_mfma_f32_16x16x32_bf16(ah.v, wH[2][kb], acc2, 0,0,0);
                acc2 = __builtin_amdgcn_mfma_f32_16x16x32_bf16(ah.v, wL[2][kb], acc2, 0,0,0);
                acc2 = __builtin_amdgcn_mfma_f32_16x16x32_bf16(al.v, wH[2][kb], acc2, 0,0,0);
                acc3 = __builtin_amdgcn_mfma_f32_16x16x32_bf16(ah.v, wH[3][kb], acc3, 0,0,0);
                acc3 = __builtin_amdgcn_mfma_f32_16x16x32_bf16(ah.v, wL[3][kb], acc3, 0,0,0);
                acc3 = __builtin_amdgcn_mfma_f32_16x16x32_bf16(al.v, wH[3][kb], acc3, 0,0,0);
                acc4 = __builtin_amdgcn_mfma_f32_16x16x32_bf16(ch.v, wH[4][kb], acc4, 0,0,0);
                acc4 = __builtin_amdgcn_mfma_f32_16x16x32_bf16(ch.v, wL[4][kb], acc4, 0,0,0);
                acc4 = __builtin_amdgcn_mfma_f32_16x16x32_bf16(cl.v, wH[4][kb], acc4, 0,0,0);
            }
            if (__all((int)((okb >> 16) & 1u))) break;
        }

        // gates for owned cells: D[row=q*4+r2][col=lane&15]
#pragma unroll
        for (int r2 = 0; r2 < 4; ++r2){
            float fpre = acc0[r2] + uF[r2] + bF;
            float ipre = acc1[r2] + uI[r2] + bI;
            float opre = acc2[r2] + uO[r2] + bO;
            float gpre = acc3[r2] + uG[r2] + bG;
            float spre = acc4[r2] + bD;

            float cs1  = tanhf(spre);
            float cadj = (c_reg[r2] - cs1) + cs1 * tt[r2];
            float fg = sigmoidf_(fpre);
            float ig = sigmoidf_(ipre);
            float og = sigmoidf_(opre);
            float gg = sigmoidf_(gpre);
            float cn = fg * cadj + ig * gg;
            float hn = og * tanhf(cn);
            c_reg[r2] = cn;

            short chi = f2bf_s(cn);
            unsigned cw = (unsigned)(unsigned short)chi
                        | ((unsigned)(unsigned short)f2bf_s(cn - bf2f_s(chi)) << 16)
                        | 0x10000u;
            short hhi = f2bf_s(hn);
            unsigned hw = (unsigned)(unsigned short)hhi
                        | ((unsigned)(unsigned short)f2bf_s(hn - bf2f_s(hhi)) << 16)
                        | 0x10000u;

            int gb = row0 + q * 4 + r2;
            int64_t oidx = (int64_t)(s + 1) * 32768 + gb * 256 + gcol;
            __hip_atomic_store(h_seq + oidx, hw, __ATOMIC_RELAXED, __HIP_MEMORY_SCOPE_AGENT);
            __hip_atomic_store(c_seq + oidx, cw, __ATOMIC_RELAXED, __HIP_MEMORY_SCOPE_AGENT);
            __builtin_nontemporal_store(hn, &feat[((int64_t)gb * 256 + s) * 256 + gcol]);
        }
    }
}

// ---------- classifier ----------
__global__ __launch_bounds__(256) void k_cls(
    const float* __restrict__ feat, const float* __restrict__ cls_w,
    const float* __restrict__ cls_b, float* __restrict__ out)
{
    int tid = threadIdx.x, lane = tid & 63, w = tid >> 6;
    int row = blockIdx.x * 4 + w;
    float4 v  = ((const float4*)(feat + (int64_t)row * 256))[lane];
    float4 cw = ((const float4*)cls_w)[lane];
    float d = v.x * cw.x + v.y * cw.y + v.z * cw.z + v.w * cw.w;
#pragma unroll
    for (int off = 32; off > 0; off >>= 1)
        d += __shfl_down(d, off, 64);
    if (lane == 0) out[row] = d + cls_b[0];
}

extern "C" void kernel_launch(void* const* d_in, const int* in_sizes, int n_in,
                              void* d_out, int out_size, void* d_ws, size_t ws_size,
                              hipStream_t stream) {
    const float* x      = (const float*)d_in[0];
    const float* stages = (const float*)d_in[1];
    const float* tsp    = (const float*)d_in[2];
    const float* se_w1  = (const float*)d_in[3];
    const float* se_b1  = (const float*)d_in[4];
    const float* se_w2  = (const float*)d_in[5];
    const float* se_b2  = (const float*)d_in[6];
    const float* se_w3  = (const float*)d_in[7];
    const float* se_b3  = (const float*)d_in[8];
    const float* W_all  = (const float*)d_in[9];
    const float* W_allb = (const float*)d_in[10];
    const float* U_w    = (const float*)d_in[11];
    const float* U_b    = (const float*)d_in[12];
    const float* W_d    = (const float*)d_in[13];
    const float* W_d_b  = (const float*)d_in[14];
    const float* cls_w  = (const float*)d_in[15];
    const float* cls_b  = (const float*)d_in[16];
    (void)in_sizes; (void)n_in; (void)out_size; (void)ws_size;

    float* out  = (float*)d_out;          // [32768]
    float* feat = out + 32768;            // [32768][256]

    char* ws = (char*)d_ws;
    short*  stagesP  = (short*)  (ws + 532480);       // 6291456 B
    short*  st1      = (short*)  (ws + 6823936);      // 16777216 B
    short*  st2      = (short*)  (ws + 23601152);     // 33554432 B
    short*  w1T      = (short*)  (ws + 57155584);     // 49152 B
    short*  w2T      = (short*)  (ws + 57204736);     // 262144 B
    short*  w3T      = (short*)  (ws + 57466880);     // 1048576 B
    short*  UwT      = (short*)  (ws + 58515456);     // 4194304 B
    short*  xin      = (short*)  (ws + 62709760);     // 134217728 B
    float*  u        = (float*)  (ws + 196927488);    // 134217728 B
    // h_seq/c_seq live in the TAIL of the xin region (dead after U-GEMM):
    // [129556480, 196927488) = 2 x 257*32768*4 B = 67,371,008 B.
    unsigned* h_seq  = (unsigned*)(ws + 129556480);
    unsigned* c_seq  = (unsigned*)(ws + 163241984);

    // conversions
    k_cvt_x<<<8388608 / 256, 256, 0, stream>>>(x, xin);
    k_cvt_stages<<<(32768 * 96) / 256, 256, 0, stream>>>(stages, stagesP);
    k_transpose<<<(256 * 96) / 256, 256, 0, stream>>>(se_w1, w1T, 67, 256, 96);
    k_transpose<<<(512 * 256) / 256, 256, 0, stream>>>(se_w2, w2T, 256, 512, 256);
    k_transpose<<<(1024 * 512) / 256, 256, 0, stream>>>(se_w3, w3T, 512, 1024, 512);
    k_transpose<<<(1024 * 2048) / 256, 256, 0, stream>>>(U_w, UwT, 2048, 1024, 2048);

    // stage MLP (bf16 MFMA, relu, bf16 out)
    k_gemm<<<dim3(2, 256), 256, 0, stream>>>(stagesP, 96, w1T, 96, se_b1, 96, 1 | 2,
                                             nullptr, st1, 256);
    k_gemm<<<dim3(4, 256), 256, 0, stream>>>(st1, 256, w2T, 256, se_b2, 256, 1 | 2,
                                             nullptr, st2, 512);
    k_gemm<<<dim3(8, 256), 256, 0, stream>>>(st2, 512, w3T, 512, se_b3, 512, 1 | 2,
                                             nullptr, xin + 1024, 2048);
    // u = xin @ U_all_w + U_all_b, stored permuted [s][b][1024] f32
    k_gemm<<<dim3(8, 256), 256, 0, stream>>>(xin, 2048, UwT, 2048, U_b, 2048, 4,
                                             u, nullptr, 1024);

    // xin now dead: clear h_seq/c_seq (sentinel-invalid) + valid-zero s=0 slices
    k_init_seq<<<16448, 256, 0, stream>>>((uint4*)h_seq);

    // sequential TLSTM scan (writes feat)
    k_scan2<<<128, 64, 0, stream>>>(W_all, W_allb, W_d, W_d_b, u, tsp,
                                    h_seq, c_seq, feat);

    // classifier
    k_cls<<<8192, 256, 0, stream>>>(feat, cls_w, cls_b, out);
}